// Round 6
// baseline (595.366 us; speedup 1.0000x reference)
//
#include <hip/hip_runtime.h>

#define NMETA 64
#define MSUB 1024
#define NNODES 65536          // NMETA*MSUB
#define D 128
#define DOUT 64
#define NEDGES 1048576
#define COLS 131072           // MSUB*D
#define BCAP 5120             // LDS capacity per bucket (mean 4096, sigma ~64)

typedef __attribute__((ext_vector_type(8))) short bf8_t;   // 8 bf16 = 4 VGPRs
typedef __attribute__((ext_vector_type(4))) float f4_t;
typedef __attribute__((ext_vector_type(2))) float f2_t;    // -> v_pk_fma_f32

__device__ inline unsigned short bfr(float x) {            // fp32 -> bf16 RNE
    unsigned u = __builtin_bit_cast(unsigned, x);
    u += 0x7fffu + ((u >> 16) & 1u);
    return (unsigned short)(u >> 16);
}
__device__ inline float b2f(unsigned short h) {
    return __builtin_bit_cast(float, (unsigned)h << 16);
}
__device__ inline f2_t up2(unsigned u) {                   // 2 bf16 -> 2 fp32
    f2_t r;
    r[0] = __builtin_bit_cast(float, u << 16);
    r[1] = __builtin_bit_cast(float, u & 0xffff0000u);
    return r;
}

// ------------------------------------------------------- CSR via 256-bucket radix
// per-wg histogram; write transposed counts (bucket-major), no global atomics
__global__ __launch_bounds__(256) void k_bhist(const int* __restrict__ dst,
                                               int* __restrict__ whist) {
    __shared__ int c[256];
    int t = threadIdx.x, w = blockIdx.x;
    c[t] = 0;
    __syncthreads();
    const int* dp = dst + w * 4096;
    for (int k = 0; k < 16; ++k) atomicAdd(&c[dp[k * 256 + t] >> 8], 1);
    __syncthreads();
    whist[t * 256 + w] = c[t];
}

// 1 block: per-bucket exclusive prefix over wgs (in place) + bucket-base scan
__global__ __launch_bounds__(256) void k_bscan(int* __restrict__ whist,
                                               int* __restrict__ bbase) {
    __shared__ int sh[256];
    int t = threadIdx.x;
    int run = 0;
    for (int w = 0; w < 256; ++w) {
        int v = whist[t * 256 + w];
        whist[t * 256 + w] = run;
        run += v;
    }
    sh[t] = run;
    __syncthreads();
    for (int d = 1; d < 256; d <<= 1) {
        int x = (t >= d) ? sh[t - d] : 0;
        __syncthreads();
        sh[t] += x;
        __syncthreads();
    }
    bbase[t] = sh[t] - run;
    if (t == 255) bbase[256] = NEDGES;
}

// scatter packed (dlow<<16 | src) into reserved per-(wg,bucket) segments
__global__ __launch_bounds__(256) void k_bscatter(const int* __restrict__ src,
                                                  const int* __restrict__ dst,
                                                  const int* __restrict__ bbase,
                                                  const int* __restrict__ whist,
                                                  unsigned* __restrict__ tmp) {
    __shared__ int cur[256];
    __shared__ int base[256];
    int t = threadIdx.x, w = blockIdx.x;
    cur[t] = 0;
    base[t] = bbase[t] + whist[t * 256 + w];
    __syncthreads();
    const int* dp = dst + w * 4096;
    const int* sp = src + w * 4096;
    for (int k = 0; k < 16; ++k) {
        int d = dp[k * 256 + t], s = sp[k * 256 + t];
        int b = d >> 8;
        int lr = atomicAdd(&cur[b], 1);
        tmp[base[b] + lr] = ((unsigned)(d & 255) << 16) | (unsigned)s;
    }
}

// one wg per bucket: build node-level CSR in LDS, write out coalesced.
__global__ __launch_bounds__(256) void k_bcsr(const unsigned* __restrict__ tmp,
                                              const int* __restrict__ bbase,
                                              int* __restrict__ offs,
                                              float* __restrict__ dinv,
                                              unsigned short* __restrict__ csr16) {
    __shared__ unsigned pairs[BCAP];
    __shared__ unsigned short image[BCAP];
    __shared__ int cnt[256], cur[256], sh[256];
    int t = threadIdx.x, b = blockIdx.x;
    int base = bbase[b], n = bbase[b + 1] - base;
    for (int i = t; i < n; i += 256) pairs[i] = tmp[base + i];
    cnt[t] = 0;
    __syncthreads();
    for (int i = t; i < n; i += 256) atomicAdd(&cnt[pairs[i] >> 16], 1);
    __syncthreads();
    int c = cnt[t];
    sh[t] = c;
    __syncthreads();
    for (int d = 1; d < 256; d <<= 1) {
        int x = (t >= d) ? sh[t - d] : 0;
        __syncthreads();
        sh[t] += x;
        __syncthreads();
    }
    int excl = sh[t] - c;
    cur[t] = excl;
    offs[b * 256 + t] = base + excl;
    dinv[b * 256 + t] = rsqrtf((float)(c + 1));
    if (b == 255 && t == 255) offs[65536] = NEDGES;
    __syncthreads();
    for (int i = t; i < n; i += 256) {
        unsigned p = pairs[i];
        int pos = atomicAdd(&cur[p >> 16], 1);
        image[pos] = (unsigned short)(p & 0xffffu);
    }
    __syncthreads();
    for (int i = t; i < n; i += 256) csr16[base + i] = image[i];
}

// --------------------------------------------- fused setup: adjpow + cvt_x + cvt_w
// block 0: adjacency powers (Ab[i][n][j] bf16, row-major)
// blocks 1..8192: x -> bf16 ; blocks 8193..9088: weights -> bf16 transposed
__global__ __launch_bounds__(256) void k_setup(const float* __restrict__ A,
                                               unsigned short* __restrict__ Ab,
                                               const float4* __restrict__ x,
                                               ushort4* __restrict__ xo,
                                               const float* __restrict__ gcnW,
                                               const float* __restrict__ W1,
                                               const float* __restrict__ W2,
                                               unsigned short* __restrict__ Wt) {
    int blk = blockIdx.x, t = threadIdx.x;
    if (blk == 0) {
        __shared__ float As[4096];
        __shared__ float Bs[4096];
        for (int q = 0; q < 16; ++q) As[t + 256 * q] = A[t + 256 * q];
        __syncthreads();
        for (int q = 0; q < 16; ++q) {
            int idx = t + 256 * q;
            int n = idx >> 6, j = idx & 63;
            Ab[idx] = bfr(As[idx]);
            float acc = 0.f;
            for (int k = 0; k < 64; ++k) acc += As[n * 64 + k] * As[k * 64 + j];
            Bs[idx] = acc;
            Ab[4096 + idx] = bfr(acc);
        }
        __syncthreads();
        for (int q = 0; q < 16; ++q) {
            int idx = t + 256 * q;
            int n = idx >> 6, j = idx & 63;
            float acc = 0.f;
            for (int k = 0; k < 64; ++k) acc += Bs[n * 64 + k] * As[k * 64 + j];
            Ab[8192 + idx] = bfr(acc);
        }
    } else if (blk <= 8192) {
        int i = (blk - 1) * 256 + t;
        float4 v = x[i];
        ushort4 u;
        u.x = bfr(v.x); u.y = bfr(v.y); u.z = bfr(v.z); u.w = bfr(v.w);
        xo[i] = u;
    } else {
        int b2 = blk - 8193;
        int m = b2 >> 6;
        int idx = (b2 & 63) * 256 + t;
        const float* src;
        int N = 128;
        if (m < 12)       src = gcnW + m * 16384;
        else if (m == 12) src = W1;
        else { src = W2; N = 64; if (idx >= 8192) return; }
        int n = idx >> 7, k = idx & 127;
        Wt[m * 16384 + idx] = bfr(src[k * N + n]);
    }
}

// ---------------------------------------------------------------- meta mix (MFMA)
// 128-col tiles (grid 1024) for occupancy; LDS pad 130 (conflict-free u16 reads)
#define CPAD 130
__global__ __launch_bounds__(256) void k_mixX(const unsigned short* __restrict__ X,
                                              const unsigned short* __restrict__ Ab,
                                              unsigned short* __restrict__ Xm) {
    __shared__ unsigned short Us[64 * CPAD];
    int t = threadIdx.x;
    long c0 = (long)blockIdx.x * 128;
    int wave = t >> 6, lane = t & 63;
    int l16 = lane & 15, kg = lane >> 4;
    for (int q = 0; q < 8; ++q) {
        int row = q * 8 + (t >> 5);
        int col = (t & 31) * 4;
        *(ushort4*)&Us[row * CPAD + col] =
            *(const ushort4*)(X + (long)row * COLS + c0 + col);
    }
    bf8_t a[3][2];
#pragma unroll
    for (int i = 0; i < 3; ++i)
#pragma unroll
        for (int kb = 0; kb < 2; ++kb)
            a[i][kb] = *(const bf8_t*)(Ab + i * 4096 + (wave * 16 + l16) * 64 +
                                       kb * 32 + kg * 8);
    __syncthreads();
    f4_t zero4 = {0.f, 0.f, 0.f, 0.f};
    for (int cs = 0; cs < 8; ++cs) {
        int cc = cs * 16 + l16;
        bf8_t b0, b1;
#pragma unroll
        for (int jj = 0; jj < 8; ++jj) {
            b0[jj] = (short)Us[(kg * 8 + jj) * CPAD + cc];
            b1[jj] = (short)Us[(32 + kg * 8 + jj) * CPAD + cc];
        }
        f4_t acc0 = zero4, acc1 = zero4, acc2 = zero4;
        acc0 = __builtin_amdgcn_mfma_f32_16x16x32_bf16(a[0][0], b0, acc0, 0, 0, 0);
        acc1 = __builtin_amdgcn_mfma_f32_16x16x32_bf16(a[1][0], b0, acc1, 0, 0, 0);
        acc2 = __builtin_amdgcn_mfma_f32_16x16x32_bf16(a[2][0], b0, acc2, 0, 0, 0);
        acc0 = __builtin_amdgcn_mfma_f32_16x16x32_bf16(a[0][1], b1, acc0, 0, 0, 0);
        acc1 = __builtin_amdgcn_mfma_f32_16x16x32_bf16(a[1][1], b1, acc1, 0, 0, 0);
        acc2 = __builtin_amdgcn_mfma_f32_16x16x32_bf16(a[2][1], b1, acc2, 0, 0, 0);
#pragma unroll
        for (int r = 0; r < 4; ++r) {
            long n = wave * 16 + kg * 4 + r;
            long o = n * COLS + c0 + cc;
            Xm[o]                        = bfr(acc0[r]);
            Xm[(long)NNODES * D + o]     = bfr(acc1[r]);
            Xm[(long)2 * NNODES * D + o] = bfr(acc2[r]);
        }
    }
}

// ----------------------------------------------------------------- fused GEMM
// 64 rows/block (grid 1024): wave handles 16 rows, K=512 via 4 z-chunks, Y bf16
__global__ __launch_bounds__(256) void k_mgemm(const unsigned short* __restrict__ X0,
                                               const unsigned short* __restrict__ Xm,
                                               const unsigned short* __restrict__ Wt4,
                                               unsigned short* __restrict__ Y) {
    int wave = threadIdx.x >> 6, lane = threadIdx.x & 63;
    int l16 = lane & 15, kg = lane >> 4;
    long row0 = (long)blockIdx.x * 64 + wave * 16;

    f4_t acc[8];
    f4_t zero4 = {0.f, 0.f, 0.f, 0.f};
#pragma unroll
    for (int nt = 0; nt < 8; ++nt) acc[nt] = zero4;

#pragma unroll
    for (int z = 0; z < 4; ++z) {
        const unsigned short* Xz = (z == 0) ? X0 : Xm + (long)(z - 1) * NNODES * D;
        const unsigned short* xp = Xz + (row0 + l16) * 128 + kg * 8;
        const unsigned short* wp = Wt4 + z * 16384 + (long)l16 * 128 + kg * 8;
#pragma unroll
        for (int kb = 0; kb < 4; ++kb) {
            bf8_t a0 = *(const bf8_t*)(xp + kb * 32);
#pragma unroll
            for (int nt = 0; nt < 8; ++nt) {
                bf8_t b = *(const bf8_t*)(wp + nt * 16 * 128 + kb * 32);
                acc[nt] = __builtin_amdgcn_mfma_f32_16x16x32_bf16(a0, b, acc[nt], 0, 0, 0);
            }
        }
    }
#pragma unroll
    for (int nt = 0; nt < 8; ++nt)
#pragma unroll
        for (int r = 0; r < 4; ++r) {
            long row = row0 + kg * 4 + r;
            int col = nt * 16 + l16;
            Y[row * 128 + col] = bfr(acc[nt][r]);
        }
}

// ----------------------------------------------------------------- MFMA GEMM (MLP)
template <int NT, bool RELU, bool OUT_BF16>
__global__ __launch_bounds__(256) void k_mfma(const unsigned short* __restrict__ X,
                                              const unsigned short* __restrict__ Wt,
                                              const float* __restrict__ bias,
                                              void* __restrict__ Cout) {
    int wave = threadIdx.x >> 6, lane = threadIdx.x & 63;
    int l16 = lane & 15, kg = lane >> 4;
    long row0 = (long)blockIdx.x * 64 + wave * 16;
    const int NCOL = NT * 16;

    bf8_t a[4];
    const unsigned short* xp = X + (row0 + l16) * 128 + kg * 8;
#pragma unroll
    for (int kb = 0; kb < 4; ++kb) a[kb] = *(const bf8_t*)(xp + kb * 32);

    f4_t acc[NT];
    f4_t zero4 = {0.f, 0.f, 0.f, 0.f};
#pragma unroll
    for (int nt = 0; nt < NT; ++nt) acc[nt] = zero4;

    const unsigned short* wp = Wt + (long)l16 * 128 + kg * 8;
#pragma unroll
    for (int kb = 0; kb < 4; ++kb)
#pragma unroll
        for (int nt = 0; nt < NT; ++nt) {
            bf8_t b = *(const bf8_t*)(wp + nt * 16 * 128 + kb * 32);
            acc[nt] = __builtin_amdgcn_mfma_f32_16x16x32_bf16(a[kb], b, acc[nt], 0, 0, 0);
        }
#pragma unroll
    for (int nt = 0; nt < NT; ++nt)
#pragma unroll
        for (int r = 0; r < 4; ++r) {
            long row = row0 + kg * 4 + r;
            int col = nt * 16 + l16;
            float v = acc[nt][r] + bias[col];
            if (RELU) v = fmaxf(v, 0.f);
            long o = row * NCOL + col;
            if (OUT_BF16) ((unsigned short*)Cout)[o] = bfr(v);
            else          ((float*)Cout)[o] = v;
        }
}

// -------------------------------------------------------------- propagation
// one node per wave; quarter-waves interleave edges (x2 unroll); packed f2 math
__global__ __launch_bounds__(256) void k_prop(const unsigned short* __restrict__ Y,
                                              const int* __restrict__ offs,
                                              const unsigned short* __restrict__ csr,
                                              const float* __restrict__ dinv,
                                              const float* __restrict__ bias4,
                                              unsigned short* __restrict__ Xout) {
    int wid = threadIdx.x >> 6;
    int lane = threadIdx.x & 63;
    int q = lane >> 4;
    int l = lane & 15;
    int v = blockIdx.x * 4 + wid;
    const uint4* Y4 = (const uint4*)Y;
    int e0 = offs[v], e1 = offs[v + 1];
    f2_t acc2[4];
#pragma unroll
    for (int k = 0; k < 4; ++k) acc2[k] = (f2_t){0.f, 0.f};

    int e = e0 + q;
    for (; e + 4 < e1; e += 8) {
        int u0 = csr[e], u1 = csr[e + 4];
        float d0 = dinv[u0], d1 = dinv[u1];
        uint4 y0 = Y4[(long)u0 * 16 + l];
        uint4 y1 = Y4[(long)u1 * 16 + l];
        f2_t dd0 = {d0, d0}, dd1 = {d1, d1};
        acc2[0] += dd0 * up2(y0.x) + dd1 * up2(y1.x);
        acc2[1] += dd0 * up2(y0.y) + dd1 * up2(y1.y);
        acc2[2] += dd0 * up2(y0.z) + dd1 * up2(y1.z);
        acc2[3] += dd0 * up2(y0.w) + dd1 * up2(y1.w);
    }
    if (e < e1) {
        int u = csr[e];
        float du = dinv[u];
        uint4 y = Y4[(long)u * 16 + l];
        f2_t dd = {du, du};
        acc2[0] += dd * up2(y.x);
        acc2[1] += dd * up2(y.y);
        acc2[2] += dd * up2(y.z);
        acc2[3] += dd * up2(y.w);
    }
    float acc[8];
#pragma unroll
    for (int k = 0; k < 4; ++k) { acc[2 * k] = acc2[k][0]; acc[2 * k + 1] = acc2[k][1]; }
#pragma unroll
    for (int k = 0; k < 8; ++k) {
        acc[k] += __shfl_xor(acc[k], 32, 64);
        acc[k] += __shfl_xor(acc[k], 16, 64);
    }
    if (q == 0) {
        float dv = dinv[v];
        float dvv = dv * dv;
        uint4 s = Y4[(long)v * 16 + l];
        f2_t s2[4] = {up2(s.x), up2(s.y), up2(s.z), up2(s.w)};
        float bs[8];
#pragma unroll
        for (int k = 0; k < 8; ++k) bs[k] = 0.f;
#pragma unroll
        for (int p = 0; p < 4; ++p) {
            float4 blo = *(const float4*)(bias4 + p * 128 + l * 8);
            float4 bhi = *(const float4*)(bias4 + p * 128 + l * 8 + 4);
            bs[0] += blo.x; bs[1] += blo.y; bs[2] += blo.z; bs[3] += blo.w;
            bs[4] += bhi.x; bs[5] += bhi.y; bs[6] += bhi.z; bs[7] += bhi.w;
        }
        unsigned r[8];
#pragma unroll
        for (int k = 0; k < 8; ++k) {
            float sf = s2[k / 2][k % 2];
            r[k] = bfr(fmaxf(dv * acc[k] + dvv * sf + bs[k], 0.f));
        }
        uint4 pk;
        pk.x = (r[1] << 16) | r[0];
        pk.y = (r[3] << 16) | r[2];
        pk.z = (r[5] << 16) | r[4];
        pk.w = (r[7] << 16) | r[6];
        ((uint4*)Xout)[(long)v * 16 + l] = pk;
    }
}

// ------------------------------------------------------------------ launch
extern "C" void kernel_launch(void* const* d_in, const int* in_sizes, int n_in,
                              void* d_out, int out_size, void* d_ws, size_t ws_size,
                              hipStream_t stream) {
    const float* x      = (const float*)d_in[0];
    const int*   subadj = (const int*)d_in[1];
    const float* adj    = (const float*)d_in[2];
    const float* gcn_W  = (const float*)d_in[3];
    const float* gcn_b  = (const float*)d_in[4];
    const float* lin_W1 = (const float*)d_in[5];
    const float* lin_b1 = (const float*)d_in[6];
    const float* lin_W2 = (const float*)d_in[7];
    const float* lin_b2 = (const float*)d_in[8];
    float* out = (float*)d_out;

    const int* e_src = subadj;
    const int* e_dst = subadj + NEDGES;

    char* w = (char*)d_ws;
    int*      whist = (int*)w;      w += (size_t)65536 * 4;
    int*      bbase = (int*)w;      w += (size_t)260 * 4;
    int*      offs  = (int*)w;      w += (size_t)65540 * 4;
    float*    dinv  = (float*)w;    w += (size_t)65536 * 4;
    unsigned* tmp   = (unsigned*)w; w += (size_t)NEDGES * 4;
    unsigned short* csr16 = (unsigned short*)w; w += (size_t)NEDGES * 2;
    unsigned short* Ab  = (unsigned short*)w; w += (size_t)3 * 4096 * 2;
    unsigned short* Xbf = (unsigned short*)w; w += (size_t)NNODES * D * 2;
    unsigned short* Xm  = (unsigned short*)w; w += (size_t)3 * NNODES * D * 2;
    unsigned short* Ybf = (unsigned short*)w; w += (size_t)NNODES * D * 2;
    unsigned short* Wt  = (unsigned short*)w; w += (size_t)14 * 16384 * 2;
    unsigned short* Hbf = (unsigned short*)w; w += (size_t)NNODES * D * 2;

    k_bhist<<<256, 256, 0, stream>>>(e_dst, whist);
    k_bscan<<<1, 256, 0, stream>>>(whist, bbase);
    k_bscatter<<<256, 256, 0, stream>>>(e_src, e_dst, bbase, whist, tmp);
    k_bcsr<<<256, 256, 0, stream>>>(tmp, bbase, offs, dinv, csr16);
    k_setup<<<9089, 256, 0, stream>>>(adj, Ab, (const float4*)x, (ushort4*)Xbf,
                                      gcn_W, lin_W1, lin_W2, Wt);

    for (int li = 0; li < 3; ++li) {
        k_mixX<<<COLS / 128, 256, 0, stream>>>(Xbf, Ab, Xm);
        k_mgemm<<<NNODES / 64, 256, 0, stream>>>(Xbf, Xm, Wt + (size_t)li * 4 * 16384, Ybf);
        k_prop<<<NNODES / 4, 256, 0, stream>>>(Ybf, offs, csr16, dinv,
                                               gcn_b + (size_t)li * 512, Xbf);
    }
    k_mfma<8, true, true><<<NNODES / 64, 256, 0, stream>>>(
        Xbf, Wt + (size_t)12 * 16384, lin_b1, Hbf);
    k_mfma<4, false, false><<<NNODES / 64, 256, 0, stream>>>(
        Hbf, Wt + (size_t)13 * 16384, lin_b2, out);
}

// Round 8
// 453.946 us; speedup vs baseline: 1.3115x; 1.3115x over previous
//
#include <hip/hip_runtime.h>

#define NMETA 64
#define MSUB 1024
#define NNODES 65536          // NMETA*MSUB
#define D 128
#define DOUT 64
#define NEDGES 1048576
#define COLS 131072           // MSUB*D
#define BCAP 5120             // LDS capacity per bucket (mean 4096, sigma ~64)

typedef __attribute__((ext_vector_type(8))) short bf8_t;   // 8 bf16 = 4 VGPRs
typedef __attribute__((ext_vector_type(4))) float f4_t;
typedef __attribute__((ext_vector_type(2))) float f2_t;    // -> v_pk_fma_f32

__device__ inline unsigned short bfr(float x) {            // fp32 -> bf16 RNE
    unsigned u = __builtin_bit_cast(unsigned, x);
    u += 0x7fffu + ((u >> 16) & 1u);
    return (unsigned short)(u >> 16);
}
__device__ inline float b2f(unsigned short h) {
    return __builtin_bit_cast(float, (unsigned)h << 16);
}
__device__ inline f2_t up2(unsigned u) {                   // 2 bf16 -> 2 fp32
    f2_t r;
    r[0] = __builtin_bit_cast(float, u << 16);
    r[1] = __builtin_bit_cast(float, u & 0xffff0000u);
    return r;
}

// ------------------------------------------------------- CSR via 256-bucket radix
__global__ __launch_bounds__(256) void k_bhist(const int* __restrict__ dst,
                                               int* __restrict__ whist) {
    __shared__ int c[256];
    int t = threadIdx.x, w = blockIdx.x;
    c[t] = 0;
    __syncthreads();
    const int* dp = dst + w * 4096;
    for (int k = 0; k < 16; ++k) atomicAdd(&c[dp[k * 256 + t] >> 8], 1);
    __syncthreads();
    whist[t * 256 + w] = c[t];
}

__global__ __launch_bounds__(256) void k_bscan(int* __restrict__ whist,
                                               int* __restrict__ bbase) {
    __shared__ int sh[256];
    int t = threadIdx.x;
    int run = 0;
    for (int w = 0; w < 256; ++w) {
        int v = whist[t * 256 + w];
        whist[t * 256 + w] = run;
        run += v;
    }
    sh[t] = run;
    __syncthreads();
    for (int d = 1; d < 256; d <<= 1) {
        int x = (t >= d) ? sh[t - d] : 0;
        __syncthreads();
        sh[t] += x;
        __syncthreads();
    }
    bbase[t] = sh[t] - run;
    if (t == 255) bbase[256] = NEDGES;
}

__global__ __launch_bounds__(256) void k_bscatter(const int* __restrict__ src,
                                                  const int* __restrict__ dst,
                                                  const int* __restrict__ bbase,
                                                  const int* __restrict__ whist,
                                                  unsigned* __restrict__ tmp) {
    __shared__ int cur[256];
    __shared__ int base[256];
    int t = threadIdx.x, w = blockIdx.x;
    cur[t] = 0;
    base[t] = bbase[t] + whist[t * 256 + w];
    __syncthreads();
    const int* dp = dst + w * 4096;
    const int* sp = src + w * 4096;
    for (int k = 0; k < 16; ++k) {
        int d = dp[k * 256 + t], s = sp[k * 256 + t];
        int b = d >> 8;
        int lr = atomicAdd(&cur[b], 1);
        tmp[base[b] + lr] = ((unsigned)(d & 255) << 16) | (unsigned)s;
    }
}

__global__ __launch_bounds__(256) void k_bcsr(const unsigned* __restrict__ tmp,
                                              const int* __restrict__ bbase,
                                              int* __restrict__ offs,
                                              float* __restrict__ dinv,
                                              unsigned short* __restrict__ csr16) {
    __shared__ unsigned pairs[BCAP];
    __shared__ unsigned short image[BCAP];
    __shared__ int cnt[256], cur[256], sh[256];
    int t = threadIdx.x, b = blockIdx.x;
    int base = bbase[b], n = bbase[b + 1] - base;
    for (int i = t; i < n; i += 256) pairs[i] = tmp[base + i];
    cnt[t] = 0;
    __syncthreads();
    for (int i = t; i < n; i += 256) atomicAdd(&cnt[pairs[i] >> 16], 1);
    __syncthreads();
    int c = cnt[t];
    sh[t] = c;
    __syncthreads();
    for (int d = 1; d < 256; d <<= 1) {
        int x = (t >= d) ? sh[t - d] : 0;
        __syncthreads();
        sh[t] += x;
        __syncthreads();
    }
    int excl = sh[t] - c;
    cur[t] = excl;
    offs[b * 256 + t] = base + excl;
    dinv[b * 256 + t] = rsqrtf((float)(c + 1));
    if (b == 255 && t == 255) offs[65536] = NEDGES;
    __syncthreads();
    for (int i = t; i < n; i += 256) {
        unsigned p = pairs[i];
        int pos = atomicAdd(&cur[p >> 16], 1);
        image[pos] = (unsigned short)(p & 0xffffu);
    }
    __syncthreads();
    for (int i = t; i < n; i += 256) csr16[base + i] = image[i];
}

// --------------------------------------------- fused setup: adjpow + cvt_x + cvt_w
__global__ __launch_bounds__(256) void k_setup(const float* __restrict__ A,
                                               unsigned short* __restrict__ Ab,
                                               const float4* __restrict__ x,
                                               ushort4* __restrict__ xo,
                                               const float* __restrict__ gcnW,
                                               const float* __restrict__ W1,
                                               const float* __restrict__ W2,
                                               unsigned short* __restrict__ Wt) {
    int blk = blockIdx.x, t = threadIdx.x;
    if (blk == 0) {
        __shared__ float As[4096];
        __shared__ float Bs[4096];
        for (int q = 0; q < 16; ++q) As[t + 256 * q] = A[t + 256 * q];
        __syncthreads();
        for (int q = 0; q < 16; ++q) {
            int idx = t + 256 * q;
            int n = idx >> 6, j = idx & 63;
            Ab[idx] = bfr(As[idx]);
            float acc = 0.f;
            for (int k = 0; k < 64; ++k) acc += As[n * 64 + k] * As[k * 64 + j];
            Bs[idx] = acc;
            Ab[4096 + idx] = bfr(acc);
        }
        __syncthreads();
        for (int q = 0; q < 16; ++q) {
            int idx = t + 256 * q;
            int n = idx >> 6, j = idx & 63;
            float acc = 0.f;
            for (int k = 0; k < 64; ++k) acc += Bs[n * 64 + k] * As[k * 64 + j];
            Ab[8192 + idx] = bfr(acc);
        }
    } else if (blk <= 8192) {
        int i = (blk - 1) * 256 + t;
        float4 v = x[i];
        ushort4 u;
        u.x = bfr(v.x); u.y = bfr(v.y); u.z = bfr(v.z); u.w = bfr(v.w);
        xo[i] = u;
    } else {
        int b2 = blk - 8193;
        int m = b2 >> 6;
        int idx = (b2 & 63) * 256 + t;
        const float* src;
        int N = 128;
        if (m < 12)       src = gcnW + m * 16384;
        else if (m == 12) src = W1;
        else { src = W2; N = 64; if (idx >= 8192) return; }
        int n = idx >> 7, k = idx & 127;
        Wt[m * 16384 + idx] = bfr(src[k * N + n]);
    }
}

// ------------------------------------------------- fused layer: mix + gemm
// One block per sub-node m. Y[:,m,:] = sum_z A_z @ (X[:,m,:] @ W_z), A_0 = I.
// T_0 kept in registers (same D-fragment lane mapping as phase-2 output).
// T_1..T_3 in LDS at full 128-col width, stride TS=130 (phase-2 reads
// conflict-free: kg row-step = 520 dwords = +8 banks). The X stage (stride
// 128) ALIASES the T buffer: xa fragments snapshot X into registers, one
// barrier, then T overwrites.
#define TS 130
__global__ __launch_bounds__(256) void k_layer(const unsigned short* __restrict__ X,
                                               const unsigned short* __restrict__ Ab,
                                               const unsigned short* __restrict__ Wt4,
                                               unsigned short* __restrict__ Y) {
    __shared__ unsigned short LB[3 * 64 * TS];   // 48.75 KB; aliased X stage first
    int t = threadIdx.x;
    int m = blockIdx.x;
    int wave = t >> 6, lane = t & 63;
    int l16 = lane & 15, kg = lane >> 4;
    int c0 = wave * 32;

    // stage X[:, m, :] as [row][128] (row stride 256B, 16B-aligned)
#pragma unroll
    for (int it = 0; it < 4; ++it) {
        int slot = it * 256 + t;
        int row = slot >> 4, ch = slot & 15;
        *(uint4*)&LB[row * 128 + ch * 8] =
            *(const uint4*)(X + ((long)row * MSUB + m) * D + ch * 8);
    }
    __syncthreads();

    // snapshot A-operand fragments of X_m (all 4 m-tiles, full K=128)
    bf8_t xa[4][4];
#pragma unroll
    for (int mt = 0; mt < 4; ++mt)
#pragma unroll
        for (int kb = 0; kb < 4; ++kb)
            xa[mt][kb] = *(const bf8_t*)&LB[(mt * 16 + l16) * 128 + kb * 32 + kg * 8];
    __syncthreads();   // everyone done reading X stage before T overwrites it

    f4_t zero4 = {0.f, 0.f, 0.f, 0.f};

    // phase 1a: T_0 = X_m @ W_0 -> registers
    f4_t accT0[4][2];
#pragma unroll
    for (int mt = 0; mt < 4; ++mt)
#pragma unroll
        for (int nt = 0; nt < 2; ++nt) accT0[mt][nt] = zero4;
#pragma unroll
    for (int kb = 0; kb < 4; ++kb)
#pragma unroll
        for (int nt = 0; nt < 2; ++nt) {
            bf8_t b = *(const bf8_t*)(Wt4 + (long)(c0 + nt * 16 + l16) * 128 +
                                      kb * 32 + kg * 8);
#pragma unroll
            for (int mt = 0; mt < 4; ++mt)
                accT0[mt][nt] = __builtin_amdgcn_mfma_f32_16x16x32_bf16(
                    xa[mt][kb], b, accT0[mt][nt], 0, 0, 0);
        }

    // phase 1b: T_z = X_m @ W_z (z=1..3) -> LDS (bf16), this wave's 32 cols
#pragma unroll
    for (int z = 1; z < 4; ++z) {
        f4_t acc[4][2];
#pragma unroll
        for (int mt = 0; mt < 4; ++mt)
#pragma unroll
            for (int nt = 0; nt < 2; ++nt) acc[mt][nt] = zero4;
        const unsigned short* wp = Wt4 + z * 16384;
#pragma unroll
        for (int kb = 0; kb < 4; ++kb)
#pragma unroll
            for (int nt = 0; nt < 2; ++nt) {
                bf8_t b = *(const bf8_t*)(wp + (long)(c0 + nt * 16 + l16) * 128 +
                                          kb * 32 + kg * 8);
#pragma unroll
                for (int mt = 0; mt < 4; ++mt)
                    acc[mt][nt] = __builtin_amdgcn_mfma_f32_16x16x32_bf16(
                        xa[mt][kb], b, acc[mt][nt], 0, 0, 0);
            }
#pragma unroll
        for (int mt = 0; mt < 4; ++mt)
#pragma unroll
            for (int nt = 0; nt < 2; ++nt)
#pragma unroll
                for (int r = 0; r < 4; ++r)
                    LB[((z - 1) * 64 + mt * 16 + kg * 4 + r) * TS +
                       c0 + nt * 16 + l16] = bfr(acc[mt][nt][r]);
    }
    // no barrier: each wave reads only its own column slab of T

    // phase 2: Y_slab = T_0 + sum_i A_i @ T_i
    f4_t acc2[4][2];
#pragma unroll
    for (int mt = 0; mt < 4; ++mt)
#pragma unroll
        for (int nt = 0; nt < 2; ++nt) acc2[mt][nt] = zero4;
#pragma unroll
    for (int i = 0; i < 3; ++i)
#pragma unroll
        for (int kb = 0; kb < 2; ++kb) {
            bf8_t af[4];
#pragma unroll
            for (int mt = 0; mt < 4; ++mt)
                af[mt] = *(const bf8_t*)(Ab + i * 4096 + (mt * 16 + l16) * 64 +
                                         kb * 32 + kg * 8);
#pragma unroll
            for (int nt = 0; nt < 2; ++nt) {
                bf8_t b;
#pragma unroll
                for (int jj = 0; jj < 8; ++jj)
                    b[jj] = (short)LB[(i * 64 + kb * 32 + kg * 8 + jj) * TS +
                                      c0 + nt * 16 + l16];
#pragma unroll
                for (int mt = 0; mt < 4; ++mt)
                    acc2[mt][nt] = __builtin_amdgcn_mfma_f32_16x16x32_bf16(
                        af[mt], b, acc2[mt][nt], 0, 0, 0);
            }
        }

#pragma unroll
    for (int mt = 0; mt < 4; ++mt)
#pragma unroll
        for (int nt = 0; nt < 2; ++nt)
#pragma unroll
            for (int r = 0; r < 4; ++r) {
                int row = mt * 16 + kg * 4 + r;
                int col = c0 + nt * 16 + l16;
                float v = acc2[mt][nt][r] + accT0[mt][nt][r];
                Y[((long)row * MSUB + m) * D + col] = bfr(v);
            }
}

// ----------------------------------------------------------------- MFMA GEMM (MLP)
// 128 rows/block, 2 m-tiles/wave (proven R5 shape)
template <int NT, bool RELU, bool OUT_BF16>
__global__ __launch_bounds__(256) void k_mfma(const unsigned short* __restrict__ X,
                                              const unsigned short* __restrict__ Wt,
                                              const float* __restrict__ bias,
                                              void* __restrict__ Cout) {
    int wave = threadIdx.x >> 6, lane = threadIdx.x & 63;
    int l16 = lane & 15, kg = lane >> 4;
    long row0 = (long)blockIdx.x * 128 + wave * 32;
    const int NCOL = NT * 16;

    bf8_t a[2][4];
    const unsigned short* xp = X + row0 * 128 + kg * 8;
#pragma unroll
    for (int kb = 0; kb < 4; ++kb) {
        a[0][kb] = *(const bf8_t*)(xp + (long)l16 * 128 + kb * 32);
        a[1][kb] = *(const bf8_t*)(xp + (long)(l16 + 16) * 128 + kb * 32);
    }
    f4_t acc[2][NT];
    f4_t zero4 = {0.f, 0.f, 0.f, 0.f};
#pragma unroll
    for (int mt = 0; mt < 2; ++mt)
#pragma unroll
        for (int nt = 0; nt < NT; ++nt) acc[mt][nt] = zero4;

    const unsigned short* wp = Wt + (long)l16 * 128 + kg * 8;
#pragma unroll
    for (int kb = 0; kb < 4; ++kb)
#pragma unroll
        for (int nt = 0; nt < NT; ++nt) {
            bf8_t b = *(const bf8_t*)(wp + nt * 16 * 128 + kb * 32);
            acc[0][nt] = __builtin_amdgcn_mfma_f32_16x16x32_bf16(a[0][kb], b, acc[0][nt], 0, 0, 0);
            acc[1][nt] = __builtin_amdgcn_mfma_f32_16x16x32_bf16(a[1][kb], b, acc[1][nt], 0, 0, 0);
        }
#pragma unroll
    for (int mt = 0; mt < 2; ++mt)
#pragma unroll
        for (int nt = 0; nt < NT; ++nt)
#pragma unroll
            for (int r = 0; r < 4; ++r) {
                long row = row0 + mt * 16 + kg * 4 + r;
                int col = nt * 16 + l16;
                float v = acc[mt][nt][r] + bias[col];
                if (RELU) v = fmaxf(v, 0.f);
                long o = row * NCOL + col;
                if (OUT_BF16) ((unsigned short*)Cout)[o] = bfr(v);
                else          ((float*)Cout)[o] = v;
            }
}

// -------------------------------------------------------------- propagation
__global__ __launch_bounds__(256) void k_prop(const unsigned short* __restrict__ Y,
                                              const int* __restrict__ offs,
                                              const unsigned short* __restrict__ csr,
                                              const float* __restrict__ dinv,
                                              const float* __restrict__ bias4,
                                              unsigned short* __restrict__ Xout) {
    int wid = threadIdx.x >> 6;
    int lane = threadIdx.x & 63;
    int q = lane >> 4;
    int l = lane & 15;
    int v = blockIdx.x * 4 + wid;
    const uint4* Y4 = (const uint4*)Y;
    int e0 = offs[v], e1 = offs[v + 1];
    f2_t acc2[4];
#pragma unroll
    for (int k = 0; k < 4; ++k) acc2[k] = (f2_t){0.f, 0.f};

    int e = e0 + q;
    for (; e + 4 < e1; e += 8) {
        int u0 = csr[e], u1 = csr[e + 4];
        float d0 = dinv[u0], d1 = dinv[u1];
        uint4 y0 = Y4[(long)u0 * 16 + l];
        uint4 y1 = Y4[(long)u1 * 16 + l];
        f2_t dd0 = {d0, d0}, dd1 = {d1, d1};
        acc2[0] += dd0 * up2(y0.x) + dd1 * up2(y1.x);
        acc2[1] += dd0 * up2(y0.y) + dd1 * up2(y1.y);
        acc2[2] += dd0 * up2(y0.z) + dd1 * up2(y1.z);
        acc2[3] += dd0 * up2(y0.w) + dd1 * up2(y1.w);
    }
    if (e < e1) {
        int u = csr[e];
        float du = dinv[u];
        uint4 y = Y4[(long)u * 16 + l];
        f2_t dd = {du, du};
        acc2[0] += dd * up2(y.x);
        acc2[1] += dd * up2(y.y);
        acc2[2] += dd * up2(y.z);
        acc2[3] += dd * up2(y.w);
    }
    float acc[8];
#pragma unroll
    for (int k = 0; k < 4; ++k) { acc[2 * k] = acc2[k][0]; acc[2 * k + 1] = acc2[k][1]; }
#pragma unroll
    for (int k = 0; k < 8; ++k) {
        acc[k] += __shfl_xor(acc[k], 32, 64);
        acc[k] += __shfl_xor(acc[k], 16, 64);
    }
    if (q == 0) {
        float dv = dinv[v];
        float dvv = dv * dv;
        uint4 s = Y4[(long)v * 16 + l];
        f2_t s2[4] = {up2(s.x), up2(s.y), up2(s.z), up2(s.w)};
        float bs[8];
#pragma unroll
        for (int k = 0; k < 8; ++k) bs[k] = 0.f;
#pragma unroll
        for (int p = 0; p < 4; ++p) {
            float4 blo = *(const float4*)(bias4 + p * 128 + l * 8);
            float4 bhi = *(const float4*)(bias4 + p * 128 + l * 8 + 4);
            bs[0] += blo.x; bs[1] += blo.y; bs[2] += blo.z; bs[3] += blo.w;
            bs[4] += bhi.x; bs[5] += bhi.y; bs[6] += bhi.z; bs[7] += bhi.w;
        }
        unsigned r[8];
#pragma unroll
        for (int k = 0; k < 8; ++k) {
            float sf = s2[k / 2][k % 2];
            r[k] = bfr(fmaxf(dv * acc[k] + dvv * sf + bs[k], 0.f));
        }
        uint4 pk;
        pk.x = (r[1] << 16) | r[0];
        pk.y = (r[3] << 16) | r[2];
        pk.z = (r[5] << 16) | r[4];
        pk.w = (r[7] << 16) | r[6];
        ((uint4*)Xout)[(long)v * 16 + l] = pk;
    }
}

// ------------------------------------------------------------------ launch
extern "C" void kernel_launch(void* const* d_in, const int* in_sizes, int n_in,
                              void* d_out, int out_size, void* d_ws, size_t ws_size,
                              hipStream_t stream) {
    const float* x      = (const float*)d_in[0];
    const int*   subadj = (const int*)d_in[1];
    const float* adj    = (const float*)d_in[2];
    const float* gcn_W  = (const float*)d_in[3];
    const float* gcn_b  = (const float*)d_in[4];
    const float* lin_W1 = (const float*)d_in[5];
    const float* lin_b1 = (const float*)d_in[6];
    const float* lin_W2 = (const float*)d_in[7];
    const float* lin_b2 = (const float*)d_in[8];
    float* out = (float*)d_out;

    const int* e_src = subadj;
    const int* e_dst = subadj + NEDGES;

    char* w = (char*)d_ws;
    int*      whist = (int*)w;      w += (size_t)65536 * 4;
    int*      bbase = (int*)w;      w += (size_t)260 * 4;
    int*      offs  = (int*)w;      w += (size_t)65540 * 4;
    float*    dinv  = (float*)w;    w += (size_t)65536 * 4;
    unsigned* tmp   = (unsigned*)w; w += (size_t)NEDGES * 4;
    unsigned short* csr16 = (unsigned short*)w; w += (size_t)NEDGES * 2;
    unsigned short* Ab  = (unsigned short*)w; w += (size_t)3 * 4096 * 2;
    unsigned short* Xbf = (unsigned short*)w; w += (size_t)NNODES * D * 2;
    unsigned short* Ybf = (unsigned short*)w; w += (size_t)NNODES * D * 2;
    unsigned short* Wt  = (unsigned short*)w; w += (size_t)14 * 16384 * 2;
    unsigned short* Hbf = (unsigned short*)w; w += (size_t)NNODES * D * 2;

    k_bhist<<<256, 256, 0, stream>>>(e_dst, whist);
    k_bscan<<<1, 256, 0, stream>>>(whist, bbase);
    k_bscatter<<<256, 256, 0, stream>>>(e_src, e_dst, bbase, whist, tmp);
    k_bcsr<<<256, 256, 0, stream>>>(tmp, bbase, offs, dinv, csr16);
    k_setup<<<9089, 256, 0, stream>>>(adj, Ab, (const float4*)x, (ushort4*)Xbf,
                                      gcn_W, lin_W1, lin_W2, Wt);

    for (int li = 0; li < 3; ++li) {
        k_layer<<<MSUB, 256, 0, stream>>>(Xbf, Ab, Wt + (size_t)li * 4 * 16384, Ybf);
        k_prop<<<NNODES / 4, 256, 0, stream>>>(Ybf, offs, csr16, dinv,
                                               gcn_b + (size_t)li * 512, Xbf);
    }
    k_mfma<8, true, true><<<NNODES / 128, 256, 0, stream>>>(
        Xbf, Wt + (size_t)12 * 16384, lin_b1, Hbf);
    k_mfma<4, false, false><<<NNODES / 128, 256, 0, stream>>>(
        Hbf, Wt + (size_t)13 * 16384, lin_b2, out);
}